// Round 5
// baseline (10477.457 us; speedup 1.0000x reference)
//
#include <hip/hip_runtime.h>

// NSAFlowLayer: B=32 flows of (P=16384, K=64), 50 iters:
//   Y' = 0.9*Y + 0.1*X0 ; S = NS_invsqrt(Y'^T Y') ; Y = relu(0.5*Y' + 0.5*Y'@S)
// R4 -> R5: (1) symmetric gram in k_fused (upper-tri only, -47% gram FMA);
// (2) k_red two-stage partials reduction (in-place, 128 blocks) so k_ns reads
// 64KB not 512KB; (3) unroll 8 hot loops. k_fused is VALU-issue-bound (m:
// VALUBusy 51%, Occ 36.6%) -> cut FMAs, not latency.

#define BATCH 32
#define NP    16384
#define NK    64
#define NITER 50
#define NSIT  8
#define EPSC  1e-8f
#define CH    64               // chunk rows staged in LDS
#define NT    256              // threads per block (k_init/k_fused)
#define NTNS  512              // threads per block (k_ns)
#define SP    68               // padded LDS stride: 16B-aligned, <=2-way banks
#define NRED  4                // reduced partials per batch after k_red

// D[a][b] += Aa * BV.b  (4x4 outer-product accumulate)
#define FMA16(D, A0, A1, A2, A3, BV) do {                                  \
  D[0][0] = fmaf(A0, BV.x, D[0][0]); D[0][1] = fmaf(A0, BV.y, D[0][1]);    \
  D[0][2] = fmaf(A0, BV.z, D[0][2]); D[0][3] = fmaf(A0, BV.w, D[0][3]);    \
  D[1][0] = fmaf(A1, BV.x, D[1][0]); D[1][1] = fmaf(A1, BV.y, D[1][1]);    \
  D[1][2] = fmaf(A1, BV.z, D[1][2]); D[1][3] = fmaf(A1, BV.w, D[1][3]);    \
  D[2][0] = fmaf(A2, BV.x, D[2][0]); D[2][1] = fmaf(A2, BV.y, D[2][1]);    \
  D[2][2] = fmaf(A2, BV.z, D[2][2]); D[2][3] = fmaf(A2, BV.w, D[2][3]);    \
  D[3][0] = fmaf(A3, BV.x, D[3][0]); D[3][1] = fmaf(A3, BV.y, D[3][1]);    \
  D[3][2] = fmaf(A3, BV.z, D[3][2]); D[3][3] = fmaf(A3, BV.w, D[3][3]);    \
} while (0)

// 2-row variant (k_ns 2x4 tiles, k_fused off-diag gram halves)
#define FMA8(D, A0, A1, BV) do {                                           \
  D[0][0] = fmaf(A0, BV.x, D[0][0]); D[0][1] = fmaf(A0, BV.y, D[0][1]);    \
  D[0][2] = fmaf(A0, BV.z, D[0][2]); D[0][3] = fmaf(A0, BV.w, D[0][3]);    \
  D[1][0] = fmaf(A1, BV.x, D[1][0]); D[1][1] = fmaf(A1, BV.y, D[1][1]);    \
  D[1][2] = fmaf(A1, BV.z, D[1][2]); D[1][3] = fmaf(A1, BV.w, D[1][3]);    \
} while (0)

// full-gram helper (k_init only; runs once)
__device__ __forceinline__ void gram_acc(const float (*sZ)[SP], int i0, int j0,
                                         float (&acc)[4][4]) {
#pragma unroll 8
  for (int r = 0; r < CH; ++r) {
    float4 zi = *(const float4*)&sZ[r][i0];
    float4 zj = *(const float4*)&sZ[r][j0];
    FMA16(acc, zi.x, zi.y, zi.z, zi.w, zj);
  }
}

// ---------------------------------------------------------------------------
// k_init: Y := X0 ; gram partials of Y'_0 (= X0)
// ---------------------------------------------------------------------------
__global__ __launch_bounds__(NT, 4) void k_init(const float* __restrict__ X0,
                                                float* __restrict__ Y,
                                                float* __restrict__ partials,
                                                int shift) {
  __shared__ float sZ[CH][SP];
  const int tid = threadIdx.x, blk = blockIdx.x;
  const int bpb = 1 << shift;
  const int b = blk >> shift, rb = blk & (bpb - 1);
  const int rpb = NP >> shift, nch = rpb / CH;
  const size_t base = ((size_t)b * NP + (size_t)rb * rpb) * NK;
  const float* __restrict__ x0 = X0 + base;
  float* __restrict__ y = Y + base;
  const int it = tid >> 4, jt = tid & 15;
  const int i0 = it * 4, j0 = jt * 4;
  float acc[4][4] = {{0.f}};

  for (int ch = 0; ch < nch; ++ch) {
    const float* xo = x0 + ch * CH * NK;
    float* yo = y + ch * CH * NK;
#pragma unroll
    for (int q = 0; q < 4; ++q) {
      int fi = (q * NT + tid) * 4;           // coalesced float4
      float4 xv = *(const float4*)(xo + fi);
      *(float4*)(yo + fi) = xv;              // Y = X0
      int r = fi >> 6, c = fi & 63;
      *(float4*)&sZ[r][c] = xv;              // 16B-aligned (SP%4==0)
    }
    __syncthreads();
    gram_acc(sZ, i0, j0, acc);
    __syncthreads();
  }
  float* p = partials + (size_t)blk * NK * NK;
#pragma unroll
  for (int a = 0; a < 4; ++a)
    *(float4*)(p + (i0 + a) * NK + j0) =
        make_float4(acc[a][0], acc[a][1], acc[a][2], acc[a][3]);
}

// ---------------------------------------------------------------------------
// k_red: in-place tree-reduce partials: group g of batch b sums its
// per_group slots into slot (g*per_group). 128 blocks -> full-chip BW.
// ---------------------------------------------------------------------------
__global__ __launch_bounds__(NT, 8) void k_red(float* __restrict__ partials,
                                               int per_group, int bpb) {
  const int blk = blockIdx.x, tid = threadIdx.x;
  const int b = blk >> 2, g = blk & 3;
  float4* base = (float4*)partials +
                 ((size_t)b * bpb + (size_t)g * per_group) * (NK * NK / 4);
#pragma unroll
  for (int q = 0; q < 4; ++q) {
    int e = q * NT + tid;                    // 1024 f4 per slot
    float4 s = base[e];
    for (int p = 1; p < per_group; ++p) {
      float4 v = base[(size_t)p * (NK * NK / 4) + e];
      s.x += v.x; s.y += v.y; s.z += v.z; s.w += v.w;
    }
    base[e] = s;                             // own elements only: no hazard
  }
}

// ---------------------------------------------------------------------------
// k_ns: per batch, M = sum of NRED reduced slots; S = NS_invsqrt(M).
// One block per batch, 512 threads, 2x4 tiles. NS iter 0: Z=I shortcut.
// ---------------------------------------------------------------------------
__global__ __launch_bounds__(NTNS, 2) void k_ns(const float* __restrict__ partials,
                                                float* __restrict__ S,
                                                int per_group, int bpb) {
  __shared__ float sA[NK][SP];   // NS "Y"
  __shared__ float sB[NK][SP];   // NS "Z"
  __shared__ float sT[NK][SP];   // NS "T"
  __shared__ float sRed[8];

  const int tid = threadIdx.x, b = blockIdx.x;
  const int it = tid >> 4, jt = tid & 15;   // it 0..31, jt 0..15
  const int i0 = it * 2, j0 = jt * 4;

  // reduce NRED slots -> M (each thread a 2x4 tile)
  float m[2][4] = {{0.f}};
  const float* pb = partials + (size_t)b * bpb * NK * NK;
#pragma unroll
  for (int g = 0; g < NRED; ++g) {
    const float* pp = pb + (size_t)g * per_group * NK * NK;
#pragma unroll
    for (int a = 0; a < 2; ++a) {
      float4 v = *(const float4*)(pp + (i0 + a) * NK + j0);
      m[a][0] += v.x; m[a][1] += v.y; m[a][2] += v.z; m[a][3] += v.w;
    }
  }
  // trace: per-thread diag partial -> wave shuffle reduce -> LDS -> broadcast
  float local = 0.f;
#pragma unroll
  for (int a = 0; a < 2; ++a)
#pragma unroll
    for (int c = 0; c < 4; ++c)
      if ((i0 + a) == (j0 + c)) local += m[a][c];
#pragma unroll
  for (int off = 32; off; off >>= 1) local += __shfl_down(local, off);
  if ((tid & 63) == 0) sRed[tid >> 6] = local;
  __syncthreads();
  float nrm = EPSC;
#pragma unroll
  for (int w = 0; w < 8; ++w) nrm += sRed[w];
  const float inv = 1.0f / nrm;

  // sA = M/nrm, sB = I
#pragma unroll
  for (int a = 0; a < 2; ++a)
#pragma unroll
    for (int c = 0; c < 4; ++c) {
      sA[i0 + a][j0 + c] = m[a][c] * inv;
      sB[i0 + a][j0 + c] = (i0 + a) == (j0 + c) ? 1.0f : 0.0f;
    }
  __syncthreads();

  // --- NS iter 0 (Z = I): T = 1.5I - 0.5*Y ; Ynew = Y@T ; Znew = T ---
  {
#pragma unroll
    for (int a = 0; a < 2; ++a)
#pragma unroll
      for (int c = 0; c < 4; ++c)
        sT[i0 + a][j0 + c] =
            (((i0 + a) == (j0 + c)) ? 1.5f : 0.0f) - 0.5f * sA[i0 + a][j0 + c];
    __syncthreads();
    float r1[2][4] = {{0.f}};
#pragma unroll 8
    for (int k = 0; k < NK; ++k) {
      float y0 = sA[i0 + 0][k], y1 = sA[i0 + 1][k];
      float4 tv = *(const float4*)&sT[k][j0];
      FMA8(r1, y0, y1, tv);
    }
    __syncthreads();
#pragma unroll
    for (int a = 0; a < 2; ++a)
#pragma unroll
      for (int c = 0; c < 4; ++c) {
        sA[i0 + a][j0 + c] = r1[a][c];
        sB[i0 + a][j0 + c] = sT[i0 + a][j0 + c];
      }
    __syncthreads();
  }

  // --- NS iters 1..7 ---
  for (int ns = 1; ns < NSIT; ++ns) {
    float d[2][4] = {{0.f}};
#pragma unroll 8
    for (int k = 0; k < NK; ++k) {
      float b0 = sB[i0 + 0][k], b1 = sB[i0 + 1][k];
      float4 av = *(const float4*)&sA[k][j0];
      FMA8(d, b0, b1, av);
    }
#pragma unroll
    for (int a = 0; a < 2; ++a)
#pragma unroll
      for (int c = 0; c < 4; ++c)
        sT[i0 + a][j0 + c] =
            (((i0 + a) == (j0 + c)) ? 1.5f : 0.0f) - 0.5f * d[a][c];
    __syncthreads();

    float r1[2][4] = {{0.f}}, r2[2][4] = {{0.f}};
#pragma unroll 8
    for (int k = 0; k < NK; ++k) {
      float y0 = sA[i0 + 0][k], y1 = sA[i0 + 1][k];
      float4 tv = *(const float4*)&sT[k][j0];
      FMA8(r1, y0, y1, tv);
      float t0 = sT[i0 + 0][k], t1 = sT[i0 + 1][k];
      float4 zv = *(const float4*)&sB[k][j0];
      FMA8(r2, t0, t1, zv);
    }
    __syncthreads();
#pragma unroll
    for (int a = 0; a < 2; ++a)
#pragma unroll
      for (int c = 0; c < 4; ++c) {
        sA[i0 + a][j0 + c] = r1[a][c];
        sB[i0 + a][j0 + c] = r2[a][c];
      }
    __syncthreads();
  }

  const float sc = 1.0f / sqrtf(nrm);
  float* Sb = S + (size_t)b * NK * NK;
#pragma unroll
  for (int a = 0; a < 2; ++a) {
    float4 v = make_float4(sB[i0 + a][j0 + 0] * sc, sB[i0 + a][j0 + 1] * sc,
                           sB[i0 + a][j0 + 2] * sc, sB[i0 + a][j0 + 3] * sc);
    *(float4*)(Sb + (i0 + a) * NK + j0) = v;
  }
}

// ---------------------------------------------------------------------------
// k_fused: Y' = 0.9Y + 0.1X0 ; Ynew = relu(0.5 Y' + 0.5 Y'@S) ; write Y.
// If !last: Z = 0.9 Ynew + 0.1 X0 into sYp in place; SYMMETRIC gram:
// 120 off-diag tiles x 2 half-threads (2x4) + 16 diag tiles (4x4); mirror
// the transpose on store. Saves 47% of gram FMA (issue-bound kernel).
// ---------------------------------------------------------------------------
__global__ __launch_bounds__(NT, 4) void k_fused(const float* __restrict__ X0,
                                                 float* __restrict__ Y,
                                                 const float* __restrict__ S,
                                                 float* __restrict__ partials,
                                                 int last, int shift) {
  __shared__ float sS[NK][NK];     // B-operand (row-major, f4 reads)
  __shared__ float sYp[CH][SP];    // A-operand / Z staging (stride 68)

  const int tid = threadIdx.x, blk = blockIdx.x;
  const int bpb = 1 << shift;
  const int b = blk >> shift, rb = blk & (bpb - 1);
  const int rpb = NP >> shift, nch = rpb / CH;
  const size_t base = ((size_t)b * NP + (size_t)rb * rpb) * NK;
  const float* __restrict__ x0 = X0 + base;
  float* __restrict__ y = Y + base;

  { // load S for this batch
    const float4* Sb = (const float4*)(S + (size_t)b * NK * NK);
    float4* d = (float4*)sS;
    for (int i = tid; i < NK * NK / 4; i += NT) d[i] = Sb[i];
  }

  const int it = tid >> 4, jt = tid & 15;
  const int i0 = it * 4, j0 = jt * 4;

  // gram role: tid<240 -> half off-diag tile (ti<tj); tid>=240 -> diag tile
  int g_ti, g_tj;
  bool g_diag;
  {
    if (tid >= 240) { g_diag = true; g_ti = g_tj = tid - 240; }
    else {
      g_diag = false;
      int p = tid >> 1;
      int t = 0, cum = 0;
      while (cum + (15 - t) <= p) { cum += 15 - t; ++t; }   // <=15 iters, once
      g_ti = t; g_tj = t + 1 + (p - cum);
    }
  }
  const int gr0 = g_ti * 4 + (g_diag ? 0 : (tid & 1) * 2);  // 2 rows (or 4 diag)
  const int gc0 = g_tj * 4;

  float acc[4][4] = {{0.f}};
  __syncthreads();

  for (int ch = 0; ch < nch; ++ch) {
    const float* xo = x0 + ch * CH * NK;
    float* yo = y + ch * CH * NK;

    // stage Y' chunk
#pragma unroll
    for (int q = 0; q < 4; ++q) {
      int fi = (q * NT + tid) * 4;
      int r = fi >> 6, c = fi & 63;
      float4 yv = *(const float4*)(yo + fi);
      float4 xv = *(const float4*)(xo + fi);
      float4 yp;
      yp.x = fmaf(0.9f, yv.x, 0.1f * xv.x);
      yp.y = fmaf(0.9f, yv.y, 0.1f * xv.y);
      yp.z = fmaf(0.9f, yv.z, 0.1f * xv.z);
      yp.w = fmaf(0.9f, yv.w, 0.1f * xv.w);
      *(float4*)&sYp[r][c] = yp;
    }
    __syncthreads();

    // dot[a][c] = (Y' @ S) tile
    float dot[4][4] = {{0.f}};
#pragma unroll 8
    for (int k = 0; k < NK; ++k) {
      float a0 = sYp[i0 + 0][k], a1 = sYp[i0 + 1][k];
      float a2 = sYp[i0 + 2][k], a3 = sYp[i0 + 3][k];
      float4 bv = *(const float4*)&sS[k][j0];
      FMA16(dot, a0, a1, a2, a3, bv);
    }
    __syncthreads();   // done reading sYp before in-place Z overwrite

    // epilogue: Ynew = relu(0.5 Y' + 0.5 dot); write Y; Z -> sYp in place
#pragma unroll
    for (int a = 0; a < 4; ++a) {
      int r = i0 + a;
      float4 ypv = *(const float4*)&sYp[r][j0];   // own tile only
      float4 yn;
      yn.x = fmaxf(fmaf(0.5f, ypv.x, 0.5f * dot[a][0]), 0.f);
      yn.y = fmaxf(fmaf(0.5f, ypv.y, 0.5f * dot[a][1]), 0.f);
      yn.z = fmaxf(fmaf(0.5f, ypv.z, 0.5f * dot[a][2]), 0.f);
      yn.w = fmaxf(fmaf(0.5f, ypv.w, 0.5f * dot[a][3]), 0.f);
      *(float4*)(yo + r * NK + j0) = yn;
      if (!last) {
        float4 xv = *(const float4*)(xo + r * NK + j0);  // L1-hot re-read
        float4 z;
        z.x = fmaf(0.9f, yn.x, 0.1f * xv.x);
        z.y = fmaf(0.9f, yn.y, 0.1f * xv.y);
        z.z = fmaf(0.9f, yn.z, 0.1f * xv.z);
        z.w = fmaf(0.9f, yn.w, 0.1f * xv.w);
        *(float4*)&sYp[r][j0] = z;                 // in place (own tile)
      }
    }
    __syncthreads();

    if (!last) {
      if (g_diag) {
#pragma unroll 8
        for (int r = 0; r < CH; ++r) {
          float4 z = *(const float4*)&sYp[r][gc0];   // rows == cols
          FMA16(acc, z.x, z.y, z.z, z.w, z);
        }
      } else {
#pragma unroll 8
        for (int r = 0; r < CH; ++r) {
          float a0 = sYp[r][gr0], a1 = sYp[r][gr0 + 1];
          float4 zb = *(const float4*)&sYp[r][gc0];
          FMA8(acc, a0, a1, zb);
        }
      }
    }
    __syncthreads();   // before next chunk's staging overwrite
  }

  if (!last) {
    float* p = partials + (size_t)blk * NK * NK;
    if (g_diag) {
#pragma unroll
      for (int a = 0; a < 4; ++a)
        *(float4*)(p + (gr0 + a) * NK + gc0) =
            make_float4(acc[a][0], acc[a][1], acc[a][2], acc[a][3]);
    } else {
      // upper tile rows (2x4)
#pragma unroll
      for (int a = 0; a < 2; ++a)
        *(float4*)(p + (gr0 + a) * NK + gc0) =
            make_float4(acc[a][0], acc[a][1], acc[a][2], acc[a][3]);
      // mirrored transpose (4x2, scalar stores)
#pragma unroll
      for (int c = 0; c < 4; ++c) {
        p[(gc0 + c) * NK + gr0 + 0] = acc[0][c];
        p[(gc0 + c) * NK + gr0 + 1] = acc[1][c];
      }
    }
  }
}

// ---------------------------------------------------------------------------
extern "C" void kernel_launch(void* const* d_in, const int* in_sizes, int n_in,
                              void* d_out, int out_size, void* d_ws,
                              size_t ws_size, hipStream_t stream) {
  (void)in_sizes; (void)n_in; (void)out_size;
  const float* X0 = (const float*)d_in[0];
  float* Y = (float*)d_out;

  const size_t slotf = (size_t)NK * NK;  // 4096 floats per partial slot
  // layout: partials[nblk] | S[BATCH]   (k_red reduces in place)
  const size_t needed5 = (((size_t)BATCH << 5) + BATCH) * slotf * sizeof(float);
  const int shift = (ws_size >= needed5) ? 5 : 4;
  const int nblk = BATCH << shift;
  const int bpb = 1 << shift;
  const int per_group = bpb / NRED;

  float* partials = (float*)d_ws;
  float* S = partials + (size_t)nblk * slotf;

  k_init<<<nblk, NT, 0, stream>>>(X0, Y, partials, shift);
  for (int t = 0; t < NITER; ++t) {
    k_red<<<BATCH * NRED, NT, 0, stream>>>(partials, per_group, bpb);
    k_ns<<<BATCH, NTNS, 0, stream>>>(partials, S, per_group, bpb);
    k_fused<<<nblk, NT, 0, stream>>>(X0, Y, S, partials,
                                     t == NITER - 1 ? 1 : 0, shift);
  }
}

// Round 6
// 8594.965 us; speedup vs baseline: 1.2190x; 1.2190x over previous
//
#include <hip/hip_runtime.h>

// NSAFlowLayer: B=32 flows of (P=16384, K=64), 50 iters:
//   Y' = 0.9*Y + 0.1*X0 ; S = NS_invsqrt(Y'^T Y') ; Y = relu(0.5*Y' + 0.5*Y'@S)
// R5 -> R6: k_fused matmuls (Y'@S and gram Z^T Z) moved to MFMA
// (mfma_f32_16x16x32_f16) with f16 hi/lo split precision (a = hi + lo/2048).
// k_ns emits S^T as f16 hi/lo; epilogue writes Zt (transposed) so all MFMA
// fragments are row-contiguous b128 LDS reads. k_red reverted (was overhead).

#define BATCH 32
#define NP    16384
#define NK    64
#define NITER 50
#define NSIT  8
#define EPSC  1e-8f
#define CH    64               // chunk rows staged in LDS
#define NT    256              // threads per block (k_init/k_fused)
#define NTNS  512              // threads per block (k_ns)
#define SP    68               // f32 LDS stride (k_init/k_ns)
#define SPH   72               // f16 LDS stride: 144B rows, 16B-aligned

using h4   = __attribute__((ext_vector_type(4))) _Float16;
using h8   = __attribute__((ext_vector_type(8))) _Float16;
using f32x4 = __attribute__((ext_vector_type(4))) float;

#define MFMA16x32(A, B, C) __builtin_amdgcn_mfma_f32_16x16x32_f16(A, B, C, 0, 0, 0)

// D[a][b] += Aa * BV.b  (4x4 outer-product accumulate, f32 VALU — k_init)
#define FMA16(D, A0, A1, A2, A3, BV) do {                                  \
  D[0][0] = fmaf(A0, BV.x, D[0][0]); D[0][1] = fmaf(A0, BV.y, D[0][1]);    \
  D[0][2] = fmaf(A0, BV.z, D[0][2]); D[0][3] = fmaf(A0, BV.w, D[0][3]);    \
  D[1][0] = fmaf(A1, BV.x, D[1][0]); D[1][1] = fmaf(A1, BV.y, D[1][1]);    \
  D[1][2] = fmaf(A1, BV.z, D[1][2]); D[1][3] = fmaf(A1, BV.w, D[1][3]);    \
  D[2][0] = fmaf(A2, BV.x, D[2][0]); D[2][1] = fmaf(A2, BV.y, D[2][1]);    \
  D[2][2] = fmaf(A2, BV.z, D[2][2]); D[2][3] = fmaf(A2, BV.w, D[2][3]);    \
  D[3][0] = fmaf(A3, BV.x, D[3][0]); D[3][1] = fmaf(A3, BV.y, D[3][1]);    \
  D[3][2] = fmaf(A3, BV.z, D[3][2]); D[3][3] = fmaf(A3, BV.w, D[3][3]);    \
} while (0)

// 2-row variant (k_ns 2x4 tiles)
#define FMA8(D, A0, A1, BV) do {                                           \
  D[0][0] = fmaf(A0, BV.x, D[0][0]); D[0][1] = fmaf(A0, BV.y, D[0][1]);    \
  D[0][2] = fmaf(A0, BV.z, D[0][2]); D[0][3] = fmaf(A0, BV.w, D[0][3]);    \
  D[1][0] = fmaf(A1, BV.x, D[1][0]); D[1][1] = fmaf(A1, BV.y, D[1][1]);    \
  D[1][2] = fmaf(A1, BV.z, D[1][2]); D[1][3] = fmaf(A1, BV.w, D[1][3]);    \
} while (0)

__device__ __forceinline__ void gram_acc(const float (*sZ)[SP], int i0, int j0,
                                         float (&acc)[4][4]) {
#pragma unroll 8
  for (int r = 0; r < CH; ++r) {
    float4 zi = *(const float4*)&sZ[r][i0];
    float4 zj = *(const float4*)&sZ[r][j0];
    FMA16(acc, zi.x, zi.y, zi.z, zi.w, zj);
  }
}

// ---------------------------------------------------------------------------
// k_init: Y := X0 ; gram partials of Y'_0 (= X0). f32 VALU, runs once.
// ---------------------------------------------------------------------------
__global__ __launch_bounds__(NT, 4) void k_init(const float* __restrict__ X0,
                                                float* __restrict__ Y,
                                                float* __restrict__ partials,
                                                int shift) {
  __shared__ float sZ[CH][SP];
  const int tid = threadIdx.x, blk = blockIdx.x;
  const int bpb = 1 << shift;
  const int b = blk >> shift, rb = blk & (bpb - 1);
  const int rpb = NP >> shift, nch = rpb / CH;
  const size_t base = ((size_t)b * NP + (size_t)rb * rpb) * NK;
  const float* __restrict__ x0 = X0 + base;
  float* __restrict__ y = Y + base;
  const int it = tid >> 4, jt = tid & 15;
  const int i0 = it * 4, j0 = jt * 4;
  float acc[4][4] = {{0.f}};

  for (int ch = 0; ch < nch; ++ch) {
    const float* xo = x0 + ch * CH * NK;
    float* yo = y + ch * CH * NK;
#pragma unroll
    for (int q = 0; q < 4; ++q) {
      int fi = (q * NT + tid) * 4;
      float4 xv = *(const float4*)(xo + fi);
      *(float4*)(yo + fi) = xv;              // Y = X0
      int r = fi >> 6, c = fi & 63;
      *(float4*)&sZ[r][c] = xv;
    }
    __syncthreads();
    gram_acc(sZ, i0, j0, acc);
    __syncthreads();
  }
  float* p = partials + (size_t)blk * NK * NK;
#pragma unroll
  for (int a = 0; a < 4; ++a)
    *(float4*)(p + (i0 + a) * NK + j0) =
        make_float4(acc[a][0], acc[a][1], acc[a][2], acc[a][3]);
}

// ---------------------------------------------------------------------------
// k_ns: per batch, M = sum(partials); S = NS_invsqrt(M). One block per batch.
// Emits S^T as f16 hi/lo pair (lo scaled by 2048) for k_fused MFMA B-frags.
// ---------------------------------------------------------------------------
__global__ __launch_bounds__(NTNS, 2) void k_ns(const float* __restrict__ partials,
                                                _Float16* __restrict__ Sthi,
                                                _Float16* __restrict__ Stlo,
                                                int npart) {
  __shared__ float sA[NK][SP];   // NS "Y"
  __shared__ float sB[NK][SP];   // NS "Z"
  __shared__ float sT[NK][SP];   // NS "T"
  __shared__ float sRed[8];

  const int tid = threadIdx.x, b = blockIdx.x;
  const int it = tid >> 4, jt = tid & 15;
  const int i0 = it * 2, j0 = jt * 4;

  // reduce partials -> M (each thread a 2x4 tile)
  float m[2][4] = {{0.f}};
  const float* pb = partials + (size_t)b * npart * NK * NK;
#pragma unroll 4
  for (int p = 0; p < npart; ++p) {
    const float* pp = pb + (size_t)p * NK * NK;
#pragma unroll
    for (int a = 0; a < 2; ++a) {
      float4 v = *(const float4*)(pp + (i0 + a) * NK + j0);
      m[a][0] += v.x; m[a][1] += v.y; m[a][2] += v.z; m[a][3] += v.w;
    }
  }
  // trace
  float local = 0.f;
#pragma unroll
  for (int a = 0; a < 2; ++a)
#pragma unroll
    for (int c = 0; c < 4; ++c)
      if ((i0 + a) == (j0 + c)) local += m[a][c];
#pragma unroll
  for (int off = 32; off; off >>= 1) local += __shfl_down(local, off);
  if ((tid & 63) == 0) sRed[tid >> 6] = local;
  __syncthreads();
  float nrm = EPSC;
#pragma unroll
  for (int w = 0; w < 8; ++w) nrm += sRed[w];
  const float inv = 1.0f / nrm;

#pragma unroll
  for (int a = 0; a < 2; ++a)
#pragma unroll
    for (int c = 0; c < 4; ++c) {
      sA[i0 + a][j0 + c] = m[a][c] * inv;
      sB[i0 + a][j0 + c] = (i0 + a) == (j0 + c) ? 1.0f : 0.0f;
    }
  __syncthreads();

  // --- NS iter 0 (Z = I): T = 1.5I - 0.5*Y ; Ynew = Y@T ; Znew = T ---
  {
#pragma unroll
    for (int a = 0; a < 2; ++a)
#pragma unroll
      for (int c = 0; c < 4; ++c)
        sT[i0 + a][j0 + c] =
            (((i0 + a) == (j0 + c)) ? 1.5f : 0.0f) - 0.5f * sA[i0 + a][j0 + c];
    __syncthreads();
    float r1[2][4] = {{0.f}};
#pragma unroll 8
    for (int k = 0; k < NK; ++k) {
      float y0 = sA[i0 + 0][k], y1 = sA[i0 + 1][k];
      float4 tv = *(const float4*)&sT[k][j0];
      FMA8(r1, y0, y1, tv);
    }
    __syncthreads();
#pragma unroll
    for (int a = 0; a < 2; ++a)
#pragma unroll
      for (int c = 0; c < 4; ++c) {
        sA[i0 + a][j0 + c] = r1[a][c];
        sB[i0 + a][j0 + c] = sT[i0 + a][j0 + c];
      }
    __syncthreads();
  }

  // --- NS iters 1..7 ---
  for (int ns = 1; ns < NSIT; ++ns) {
    float d[2][4] = {{0.f}};
#pragma unroll 8
    for (int k = 0; k < NK; ++k) {
      float b0 = sB[i0 + 0][k], b1 = sB[i0 + 1][k];
      float4 av = *(const float4*)&sA[k][j0];
      FMA8(d, b0, b1, av);
    }
#pragma unroll
    for (int a = 0; a < 2; ++a)
#pragma unroll
      for (int c = 0; c < 4; ++c)
        sT[i0 + a][j0 + c] =
            (((i0 + a) == (j0 + c)) ? 1.5f : 0.0f) - 0.5f * d[a][c];
    __syncthreads();

    float r1[2][4] = {{0.f}}, r2[2][4] = {{0.f}};
#pragma unroll 8
    for (int k = 0; k < NK; ++k) {
      float y0 = sA[i0 + 0][k], y1 = sA[i0 + 1][k];
      float4 tv = *(const float4*)&sT[k][j0];
      FMA8(r1, y0, y1, tv);
      float t0 = sT[i0 + 0][k], t1 = sT[i0 + 1][k];
      float4 zv = *(const float4*)&sB[k][j0];
      FMA8(r2, t0, t1, zv);
    }
    __syncthreads();
#pragma unroll
    for (int a = 0; a < 2; ++a)
#pragma unroll
      for (int c = 0; c < 4; ++c) {
        sA[i0 + a][j0 + c] = r1[a][c];
        sB[i0 + a][j0 + c] = r2[a][c];
      }
    __syncthreads();
  }

  // emit S^T f16 hi/lo (lo scaled by 2048)
  const float sc = 1.0f / sqrtf(nrm);
  _Float16* Sh = Sthi + (size_t)b * NK * NK;
  _Float16* Sl = Stlo + (size_t)b * NK * NK;
#pragma unroll
  for (int a = 0; a < 2; ++a)
#pragma unroll
    for (int c = 0; c < 4; ++c) {
      float s = sB[i0 + a][j0 + c] * sc;
      _Float16 hh = (_Float16)s;
      Sh[(j0 + c) * NK + (i0 + a)] = hh;                         // transposed
      Sl[(j0 + c) * NK + (i0 + a)] = (_Float16)((s - (float)hh) * 2048.f);
    }
}

// ---------------------------------------------------------------------------
// k_fused (MFMA): Y' = 0.9Y+0.1X0 ; Ynew = relu(0.5Y' + 0.5 Y'@S) ; write Y.
// If !last: Z = 0.9Ynew+0.1X0 written transposed (f16 hi/lo) into sYa/sYb,
// gram Z^T Z accumulated in registers via MFMA, stored once at the end.
// 4 waves, each owns output rows 16w..16w+15 -> all waves identical work.
// LDS: 4 x [64][72] f16 = 36.9 KB -> 4 blocks/CU.
// ---------------------------------------------------------------------------
__global__ __launch_bounds__(NT, 4) void k_fused(
    const float* __restrict__ X0, float* __restrict__ Y,
    const _Float16* __restrict__ Sthi, const _Float16* __restrict__ Stlo,
    float* __restrict__ partials, int last, int shift) {
  __shared__ _Float16 sYa[CH][SPH];  // Y' hi  -> Zt hi after epilogue
  __shared__ _Float16 sYb[CH][SPH];  // Y' lo  -> Zt lo
  __shared__ _Float16 sSa[NK][SPH];  // S^T hi
  __shared__ _Float16 sSb[NK][SPH];  // S^T lo

  const int tid = threadIdx.x, blk = blockIdx.x;
  const int bpb = 1 << shift;
  const int b = blk >> shift, rb = blk & (bpb - 1);
  const int rpb = NP >> shift, nch = rpb / CH;
  const size_t base = ((size_t)b * NP + (size_t)rb * rpb) * NK;
  const float* __restrict__ x0 = X0 + base;
  float* __restrict__ y = Y + base;

  { // stage S^T hi/lo into LDS (each thread: 16 f16 = 32B per array)
    const _Float16* sh = Sthi + (size_t)b * NK * NK;
    const _Float16* sl = Stlo + (size_t)b * NK * NK;
    int r = tid >> 2, c = (tid & 3) * 16;
    const uint4* gh = (const uint4*)(sh + r * NK + c);
    const uint4* gl = (const uint4*)(sl + r * NK + c);
    uint4* dh = (uint4*)&sSa[r][c];
    uint4* dl = (uint4*)&sSb[r][c];
    dh[0] = gh[0]; dh[1] = gh[1];
    dl[0] = gl[0]; dl[1] = gl[1];
  }

  const int wv = tid >> 6, ln = tid & 63;
  const int lr = ln & 15, lq = ln >> 4;    // fragment row / k-group

  f32x4 gacc[4], glo[4];
#pragma unroll
  for (int t = 0; t < 4; ++t) {
    gacc[t] = (f32x4){0.f, 0.f, 0.f, 0.f};
    glo[t]  = (f32x4){0.f, 0.f, 0.f, 0.f};
  }
  __syncthreads();

  for (int ch = 0; ch < nch; ++ch) {
    const float* xo = x0 + ch * CH * NK;
    float* yo = y + ch * CH * NK;

    // ---- stage Y' as f16 hi/lo ----
#pragma unroll
    for (int q = 0; q < 4; ++q) {
      int fi = (q * NT + tid) * 4;
      int r = fi >> 6, c = fi & 63;
      float4 yv = *(const float4*)(yo + fi);
      float4 xv = *(const float4*)(xo + fi);
      float p0 = fmaf(0.9f, yv.x, 0.1f * xv.x);
      float p1 = fmaf(0.9f, yv.y, 0.1f * xv.y);
      float p2 = fmaf(0.9f, yv.z, 0.1f * xv.z);
      float p3 = fmaf(0.9f, yv.w, 0.1f * xv.w);
      _Float16 h0 = (_Float16)p0, h1 = (_Float16)p1;
      _Float16 h2 = (_Float16)p2, h3 = (_Float16)p3;
      *(h4*)&sYa[r][c] = (h4){h0, h1, h2, h3};
      *(h4*)&sYb[r][c] = (h4){(_Float16)((p0 - (float)h0) * 2048.f),
                              (_Float16)((p1 - (float)h1) * 2048.f),
                              (_Float16)((p2 - (float)h2) * 2048.f),
                              (_Float16)((p3 - (float)h3) * 2048.f)};
    }
    __syncthreads();

    // ---- dot = Y' @ S via MFMA; wave w owns rows 16w..16w+15 ----
    h8 a_hi[2], a_lo[2];
#pragma unroll
    for (int kh = 0; kh < 2; ++kh) {
      a_hi[kh] = *(const h8*)&sYa[16 * wv + lr][lq * 8 + 32 * kh];
      a_lo[kh] = *(const h8*)&sYb[16 * wv + lr][lq * 8 + 32 * kh];
    }
    f32x4 dot[4];
    float ypv[4][4];
#pragma unroll
    for (int tc = 0; tc < 4; ++tc) {
      f32x4 ah = (f32x4){0.f, 0.f, 0.f, 0.f};
      f32x4 al = (f32x4){0.f, 0.f, 0.f, 0.f};
#pragma unroll
      for (int kh = 0; kh < 2; ++kh) {
        h8 b_hi = *(const h8*)&sSa[16 * tc + lr][lq * 8 + 32 * kh];
        h8 b_lo = *(const h8*)&sSb[16 * tc + lr][lq * 8 + 32 * kh];
        ah = MFMA16x32(a_hi[kh], b_hi, ah);
        al = MFMA16x32(a_hi[kh], b_lo, al);
        al = MFMA16x32(a_lo[kh], b_hi, al);
      }
      dot[tc] = ah + al * (1.f / 2048.f);
      // y' values for epilogue (read before Zt overwrite)
#pragma unroll
      for (int r_ = 0; r_ < 4; ++r_) {
        int R = 16 * wv + 4 * lq + r_, C = 16 * tc + lr;
        ypv[tc][r_] = (float)sYa[R][C] + (float)sYb[R][C] * (1.f / 2048.f);
      }
    }
    __syncthreads();   // all sYa/sYb reads complete

    // ---- epilogue: Ynew -> global; Zt (f16 hi/lo) -> sYa/sYb ----
#pragma unroll
    for (int tc = 0; tc < 4; ++tc) {
#pragma unroll
      for (int r_ = 0; r_ < 4; ++r_) {
        int R = 16 * wv + 4 * lq + r_, C = 16 * tc + lr;
        float yn = fmaxf(0.5f * ypv[tc][r_] + 0.5f * dot[tc][r_], 0.f);
        yo[R * NK + C] = yn;
        if (!last) {
          float z = fmaf(0.9f, yn, 0.1f * xo[R * NK + C]);
          _Float16 zh = (_Float16)z;
          sYa[C][R] = zh;                                    // transposed
          sYb[C][R] = (_Float16)((z - (float)zh) * 2048.f);
        }
      }
    }
    __syncthreads();

    // ---- gram += Z^T Z via MFMA (A,B frags both from Zt) ----
    if (!last) {
      h8 ga_hi[2], ga_lo[2];
#pragma unroll
      for (int kh = 0; kh < 2; ++kh) {
        ga_hi[kh] = *(const h8*)&sYa[16 * wv + lr][lq * 8 + 32 * kh];
        ga_lo[kh] = *(const h8*)&sYb[16 * wv + lr][lq * 8 + 32 * kh];
      }
#pragma unroll
      for (int tc = 0; tc < 4; ++tc) {
        f32x4 lt = (f32x4){0.f, 0.f, 0.f, 0.f};
#pragma unroll
        for (int kh = 0; kh < 2; ++kh) {
          h8 gb_hi = *(const h8*)&sYa[16 * tc + lr][lq * 8 + 32 * kh];
          h8 gb_lo = *(const h8*)&sYb[16 * tc + lr][lq * 8 + 32 * kh];
          gacc[tc] = MFMA16x32(ga_hi[kh], gb_hi, gacc[tc]);
          lt = MFMA16x32(ga_hi[kh], gb_lo, lt);
          lt = MFMA16x32(ga_lo[kh], gb_hi, lt);
        }
        glo[tc] += lt;
      }
    }
    __syncthreads();   // before next chunk's staging overwrite
  }

  if (!last) {
    float* p = partials + (size_t)blk * NK * NK;
#pragma unroll
    for (int tc = 0; tc < 4; ++tc)
#pragma unroll
      for (int r_ = 0; r_ < 4; ++r_) {
        int R = 16 * wv + 4 * lq + r_, C = 16 * tc + lr;
        p[R * NK + C] = gacc[tc][r_] + glo[tc][r_] * (1.f / 2048.f);
      }
  }
}

// ---------------------------------------------------------------------------
extern "C" void kernel_launch(void* const* d_in, const int* in_sizes, int n_in,
                              void* d_out, int out_size, void* d_ws,
                              size_t ws_size, hipStream_t stream) {
  (void)in_sizes; (void)n_in; (void)out_size;
  const float* X0 = (const float*)d_in[0];
  float* Y = (float*)d_out;

  const size_t slotf = (size_t)NK * NK;                    // 4096
  const size_t need5 = ((size_t)(BATCH << 5)) * slotf * 4  // partials 16.8MB
                       + 2 * (size_t)BATCH * slotf * 2;    // St hi/lo 0.5MB
  const int shift = (ws_size >= need5) ? 5 : 4;
  const int nblk = BATCH << shift;

  float* partials = (float*)d_ws;
  _Float16* Sthi = (_Float16*)((char*)d_ws + (size_t)nblk * slotf * 4);
  _Float16* Stlo = Sthi + (size_t)BATCH * slotf;

  k_init<<<nblk, NT, 0, stream>>>(X0, Y, partials, shift);
  for (int t = 0; t < NITER; ++t) {
    k_ns<<<BATCH, NTNS, 0, stream>>>(partials, Sthi, Stlo, 1 << shift);
    k_fused<<<nblk, NT, 0, stream>>>(X0, Y, Sthi, Stlo, partials,
                                     t == NITER - 1 ? 1 : 0, shift);
  }
}